// Round 6
// baseline (498.059 us; speedup 1.0000x reference)
//
#include <hip/hip_runtime.h>
#include <math.h>

// Problem constants
#define C 256
#define K 1024
#define SS 4096          // 16*16*16 spatial
#define NB 8             // batch
#define NN 32768         // NB*SS rows
#define ZQ_ELEMS 8388608 // NB*C*SS
#define OUT_LOSS 8388608
#define OUT_PERP 8388609
#define OUT_IDX  8388610
#define OUT_MD   8421378

// workspace float layout
#define WS_SZ2   0       // sum z^2 (scalar)
#define WS_SE2   1       // sum e^2 (scalar)
#define WS_LOSS  2       // sum (zq-z)^2 (scalar)
#define WS_ZSUM  8       // [256] column sums of zf
#define WS_ESUM  264     // [256] column sums of emb
#define WS_CNT   520     // [1024] histogram (float)
#define WS_E2R   1544    // [1024] ||e_k||^2, numpy-pairwise f32
#define WS_Z2N   2568    // [32768] ||z_n||^2, numpy-pairwise f32
#define WS_FLG   35336   // int region: [0]=count, [1..NN]=rows
#define WS_EH    68608   // [1024*256] u16 emb-hi (131072 floats)
#define WS_EL    199680  // [1024*256] u16 emb-lo

#define T_FLAG 1.0e-4f

typedef __attribute__((ext_vector_type(8))) short short8;
typedef __attribute__((ext_vector_type(4))) float f32x4;
typedef unsigned short u16;

__device__ inline u16 f2bf(float x) {  // f32 -> bf16 RNE
  unsigned u = __float_as_uint(x);
  unsigned r = (u + 0x7fffu + ((u >> 16) & 1u)) >> 16;
  return (u16)r;
}
__device__ inline float bf2f(u16 h) { return __uint_as_float(((unsigned)h) << 16); }

// ---- numpy pairwise f32 sum of squares, 256 contiguous elements ----
__device__ inline float np_sumsq_256(const float* __restrict__ a) {
  float tot = 0.f;
  #pragma unroll
  for (int h = 0; h < 2; ++h) {
    const float* p = a + 128 * h;
    float r[8];
    #pragma unroll
    for (int j = 0; j < 8; ++j) r[j] = __fmul_rn(p[j], p[j]);
    for (int i = 8; i < 128; i += 8) {
      #pragma unroll
      for (int j = 0; j < 8; ++j) {
        float v = p[i + j];
        r[j] = __fadd_rn(r[j], __fmul_rn(v, v));
      }
    }
    float s01 = __fadd_rn(r[0], r[1]);
    float s23 = __fadd_rn(r[2], r[3]);
    float s45 = __fadd_rn(r[4], r[5]);
    float s67 = __fadd_rn(r[6], r[7]);
    float res = __fadd_rn(__fadd_rn(s01, s23), __fadd_rn(s45, s67));
    tot = (h == 0) ? res : __fadd_rn(tot, res);
  }
  return tot;
}

// ---------- emb prep: split to eh/el, e2[k], col sums, Se2 ----------
__global__ __launch_bounds__(256)
void emb_prep_k(const float* __restrict__ emb, float* __restrict__ ws,
                u16* __restrict__ eh, u16* __restrict__ el) {
  int r0 = blockIdx.x * 16;   // 64 blocks x 16 rows
  int t = threadIdx.x;
  float s = 0.f;
  #pragma unroll
  for (int i = 0; i < 16; ++i) {
    size_t idx = (size_t)(r0 + i) * C + t;
    float v = emb[idx];
    s += v;
    u16 h = f2bf(v);
    eh[idx] = h;
    el[idx] = f2bf(v - bf2f(h));
  }
  atomicAdd(&ws[WS_ESUM + t], s);
  if (t < 16) {
    float e2 = np_sumsq_256(emb + (size_t)(r0 + t) * C);
    ws[WS_E2R + r0 + t] = e2;
    atomicAdd(&ws[WS_SE2], e2);
  }
}

#define MROWS 64
#define ZS_STRIDE 260

// ---------- one pass over z: zsum[c], Sz2, z2np[n], bf16 split zh/zl ----------
__global__ __launch_bounds__(256)
void prep_z_k(const float* __restrict__ z, float* __restrict__ ws,
              u16* __restrict__ zh_g, u16* __restrict__ zl_g) {
  __shared__ float zs[MROWS * ZS_STRIDE];
  const int t = threadIdx.x;
  const int n0 = blockIdx.x * MROWS;
  const int b = n0 / SS;
  const int s0 = n0 % SS;
  {
    const int sl = t & 63, cg = t >> 6;
    const float* zb = z + (size_t)b * C * SS + s0 + sl;
    #pragma unroll
    for (int i = 0; i < 16; ++i) {
      int c = (cg * 16 + i) * 4;
      float4 v;
      v.x = zb[(size_t)(c + 0) * SS];
      v.y = zb[(size_t)(c + 1) * SS];
      v.z = zb[(size_t)(c + 2) * SS];
      v.w = zb[(size_t)(c + 3) * SS];
      *(float4*)&zs[sl * ZS_STRIDE + c] = v;
    }
  }
  __syncthreads();
  // column sums
  {
    float s = 0.f;
    #pragma unroll 8
    for (int r = 0; r < MROWS; ++r) s += zs[r * ZS_STRIDE + t];
    atomicAdd(&ws[WS_ZSUM + t], s);
  }
  // bf16 split, lane-linear coalesced short8 stores
  {
    #pragma unroll
    for (int i = 0; i < 8; ++i) {
      int q = i * 256 + t;          // short8 chunk 0..2047
      int row = q >> 5;             // 0..63
      int c0 = (q & 31) * 8;
      float4 va = *(const float4*)&zs[row * ZS_STRIDE + c0];
      float4 vb = *(const float4*)&zs[row * ZS_STRIDE + c0 + 4];
      float f[8] = {va.x, va.y, va.z, va.w, vb.x, vb.y, vb.z, vb.w};
      short8 hv, lv;
      #pragma unroll
      for (int j = 0; j < 8; ++j) {
        u16 h = f2bf(f[j]);
        hv[j] = (short)h;
        lv[j] = (short)f2bf(f[j] - bf2f(h));
      }
      size_t off = (size_t)(n0 + row) * C + c0;
      *(short8*)&zh_g[off] = hv;
      *(short8*)&zl_g[off] = lv;
    }
  }
  // z2 (numpy-pairwise) + Sz2
  if (t < MROWS) {
    float z2 = np_sumsq_256(&zs[t * ZS_STRIDE]);
    ws[WS_Z2N + n0 + t] = z2;
    #pragma unroll
    for (int off = 32; off; off >>= 1) z2 += __shfl_down(z2, off);
    if (t == 0) atomicAdd(&ws[WS_SZ2], z2);
  }
}

// ---------- main: split-bf16 MFMA distances + top-2 argmin + flags ----------
// grid 256 x 256. Block 128 rows x K. n-tiles BN=256. Waves 2x2: wave(wm,wn)
// owns rows wm*64..+63 (mi=4 of 16) x cols wn*128..+127 (ni=8 of 16).
// LDS: Ahl[128][128 u16] (h|l interleaved granules, 16-gran XOR swizzle),
// Bhl[256][128 u16], e2s[256], running top2 rv1/rv2/ri1[256]. 100 KB.
#define BM 128
#define BN 256
#define CHK 64

__global__ __launch_bounds__(256, 1)
void vq_mfma_k(const u16* __restrict__ zh_g, const u16* __restrict__ zl_g,
               const u16* __restrict__ eh_g, const u16* __restrict__ el_g,
               const float* __restrict__ e2row, float* __restrict__ out_idx,
               int* __restrict__ flags) {
  extern __shared__ u16 smem_u16[];
  u16* Ahl = smem_u16;              // 128*128 u16
  u16* Bhl = Ahl + BM * 128;        // 256*128 u16
  float* e2s = (float*)(Bhl + BN * 128);  // [256]
  float* rv1 = e2s + 256;           // [256] = 4 waves * 64 rows
  float* rv2 = rv1 + 256;
  float* ri1 = rv2 + 256;

  const int t = threadIdx.x;
  const int lane = t & 63;
  const int wid = t >> 6;
  const int wm = wid >> 1, wn = wid & 1;
  const int quad = lane >> 4, lr = lane & 15;
  const int row0 = blockIdx.x * BM;

  rv1[t] = 3.4e38f; rv2[t] = 3.4e38f; ri1[t] = 0.f;

  for (int nt = 0; nt < K / BN; ++nt) {
    const int kc0 = nt * BN;
    f32x4 acc[4][8];
    #pragma unroll
    for (int mi = 0; mi < 4; ++mi)
      #pragma unroll
      for (int ni = 0; ni < 8; ++ni) acc[mi][ni] = (f32x4){0.f, 0.f, 0.f, 0.f};

    for (int ch = 0; ch < C / CHK; ++ch) {
      const int c0 = ch * CHK;
      __syncthreads();   // prior readers done (also covers rv init)
      // stage A: 2048 granules of 16B
      #pragma unroll
      for (int i = 0; i < 8; ++i) {
        int G = i * 256 + t;
        int row = G >> 4, g = G & 15;
        const u16* srcp = (g < 8) ? zh_g : zl_g;
        short8 v = *(const short8*)&srcp[(size_t)(row0 + row) * C + c0 + (g & 7) * 8];
        *(short8*)&Ahl[row * 128 + (g ^ (row & 15)) * 8] = v;
      }
      // stage B: 4096 granules
      #pragma unroll
      for (int i = 0; i < 16; ++i) {
        int G = i * 256 + t;
        int row = G >> 4, g = G & 15;
        const u16* srcp = (g < 8) ? eh_g : el_g;
        short8 v = *(const short8*)&srcp[(size_t)(kc0 + row) * C + c0 + (g & 7) * 8];
        *(short8*)&Bhl[row * 128 + (g ^ (row & 15)) * 8] = v;
      }
      if (ch == 0) e2s[t] = e2row[kc0 + t];
      __syncthreads();
      // compute: 2 k-steps of 32
      #pragma unroll
      for (int s = 0; s < 2; ++s) {
        const int gh = 4 * s + quad;   // h granule; l granule = gh+8
        short8 ah[4], al[4];
        #pragma unroll
        for (int mi = 0; mi < 4; ++mi) {
          int row = wm * 64 + mi * 16 + lr;
          ah[mi] = *(short8*)&Ahl[row * 128 + ((gh) ^ (row & 15)) * 8];
          al[mi] = *(short8*)&Ahl[row * 128 + ((gh + 8) ^ (row & 15)) * 8];
        }
        #pragma unroll
        for (int ni = 0; ni < 8; ++ni) {
          int col = wn * 128 + ni * 16 + lr;
          short8 bh = *(short8*)&Bhl[col * 128 + ((gh) ^ (col & 15)) * 8];
          short8 bl = *(short8*)&Bhl[col * 128 + ((gh + 8) ^ (col & 15)) * 8];
          #pragma unroll
          for (int mi = 0; mi < 4; ++mi) {
            acc[mi][ni] = __builtin_amdgcn_mfma_f32_16x16x32_bf16(ah[mi], bh, acc[mi][ni], 0, 0, 0);
            acc[mi][ni] = __builtin_amdgcn_mfma_f32_16x16x32_bf16(ah[mi], bl, acc[mi][ni], 0, 0, 0);
            acc[mi][ni] = __builtin_amdgcn_mfma_f32_16x16x32_bf16(al[mi], bh, acc[mi][ni], 0, 0, 0);
          }
        }
      }
    }
    // scoring: u = e2 - 2*g; lane-local top2 over ni, butterfly over 16 col
    // lanes, writer lane updates per-wave running arrays in LDS.
    #pragma unroll
    for (int mi = 0; mi < 4; ++mi)
      #pragma unroll
      for (int reg = 0; reg < 4; ++reg) {
        float b1 = 3.4e38f, b2 = 3.4e38f, bi = 0.f;
        #pragma unroll
        for (int ni = 0; ni < 8; ++ni) {
          int col = wn * 128 + ni * 16 + lr;
          float u = fmaf(-2.f, acc[mi][ni][reg], e2s[col]);
          float ki = (float)(kc0 + col);
          if (u < b1) { b2 = b1; b1 = u; bi = ki; }
          else if (u < b2) b2 = u;
        }
        #pragma unroll
        for (int off = 1; off < 16; off <<= 1) {
          float o1 = __shfl_xor(b1, off);
          float oi = __shfl_xor(bi, off);
          float o2 = __shfl_xor(b2, off);
          bool take = (o1 < b1) || (o1 == b1 && oi < bi);
          float n2 = fminf(fminf(b2, o2), take ? b1 : o1);
          if (take) { b1 = o1; bi = oi; }
          b2 = n2;
        }
        if (lr == 0) {
          int off = wid * 64 + mi * 16 + quad * 4 + reg;
          float r1 = rv1[off];
          if (b1 < r1) { rv2[off] = fminf(r1, b2); rv1[off] = b1; ri1[off] = bi; }
          else rv2[off] = fminf(rv2[off], b1);
        }
      }
  }
  __syncthreads();
  // final: merge the two waves sharing each row half
  if (t < BM) {
    int wmr = t >> 6;
    int o0 = (wmr * 2) * 64 + (t & 63);
    int o1 = (wmr * 2 + 1) * 64 + (t & 63);
    float a1 = rv1[o0], ai = ri1[o0], a2 = rv2[o0];
    float c1 = rv1[o1], ci = ri1[o1], c2 = rv2[o1];
    bool take = (c1 < a1) || (c1 == a1 && ci < ai);
    float v1 = take ? c1 : a1;
    float vi = take ? ci : ai;
    float v2 = fminf(fminf(a2, c2), take ? a1 : c1);
    out_idx[row0 + t] = vi;
    if (v2 - v1 < T_FLAG) {
      int p = atomicAdd(&flags[0], 1);
      if (p < NN) flags[1 + p] = row0 + t;
    }
  }
}

// ---------- fixup: exactly-rounded f32 dot (via f64) + quantized formula ----------
__global__ __launch_bounds__(256)
void fixup_k(const float* __restrict__ z, const float* __restrict__ emb,
             const float* __restrict__ e2np, const float* __restrict__ z2np,
             const int* __restrict__ flags, float* __restrict__ out_idx) {
  __shared__ float zrow[C];
  __shared__ float bval[4];
  __shared__ int   bidx[4];
  int cnt = flags[0];
  if (cnt > NN) cnt = NN;
  for (int f = blockIdx.x; f < cnt; f += gridDim.x) {
    int n = flags[1 + f];
    int b = n >> 12, s = n & (SS - 1);
    int t = threadIdx.x;
    zrow[t] = z[((size_t)(b * C + t) << 12) + s];
    __syncthreads();
    float z2 = z2np[n];
    float best = 3.4e38f; int besti = 0x7fffffff;
    for (int kk = t; kk < K; kk += 256) {
      const float* er = emb + (size_t)kk * C;
      double acc = 0.0;
      #pragma unroll 4
      for (int c = 0; c < C; ++c)
        acc = fma((double)zrow[c], (double)er[c], acc);
      float g  = (float)acc;
      float t1 = __fadd_rn(z2, e2np[kk]);
      float d  = __fsub_rn(t1, __fmul_rn(2.f, g));
      if (d < best) { best = d; besti = kk; }
    }
    #pragma unroll
    for (int off = 32; off; off >>= 1) {
      float ov = __shfl_down(best, off);
      int   oi = __shfl_down(besti, off);
      if (ov < best || (ov == best && oi < besti)) { best = ov; besti = oi; }
    }
    int lane = t & 63, w = t >> 6;
    if (lane == 0) { bval[w] = best; bidx[w] = besti; }
    __syncthreads();
    if (t == 0) {
      #pragma unroll
      for (int w2 = 1; w2 < 4; ++w2) {
        if (bval[w2] < best || (bval[w2] == best && bidx[w2] < besti)) {
          best = bval[w2]; besti = bidx[w2];
        }
      }
      out_idx[n] = (float)besti;
    }
    __syncthreads();
  }
}

// ---------- gather zq + loss + histogram (fused) ----------
__global__ __launch_bounds__(256)
void gather_loss_k(const float* __restrict__ z, const float* __restrict__ emb,
                   float* __restrict__ out, float* __restrict__ ws,
                   float* __restrict__ counts) {
  __shared__ float sc[4];
  int f = blockIdx.x * 256 + threadIdx.x;  // float4 id
  int i = f << 2;
  int b = i >> 20;
  int rem = i & ((1 << 20) - 1);
  int c = rem >> 12;
  int s = rem & (SS - 1);
  int n = (b << 12) | s;
  const float* idxf = out + OUT_IDX;
  float2 ia = *(const float2*)(idxf + n);
  float2 ib = *(const float2*)(idxf + n + 2);
  int i0 = (int)ia.x, i1 = (int)ia.y, i2 = (int)ib.x, i3 = (int)ib.y;
  float4 q;
  q.x = emb[(size_t)i0 * C + c];
  q.y = emb[(size_t)i1 * C + c];
  q.z = emb[(size_t)i2 * C + c];
  q.w = emb[(size_t)i3 * C + c];
  float4 zv = *(const float4*)(z + i);
  float dx = q.x - zv.x, dy = q.y - zv.y, dz = q.z - zv.z, dw = q.w - zv.w;
  float l = dx * dx + dy * dy + dz * dz + dw * dw;
  *(float4*)(out + i) = q;
  if (c == 0) {
    atomicAdd(&counts[i0], 1.0f);
    atomicAdd(&counts[i1], 1.0f);
    atomicAdd(&counts[i2], 1.0f);
    atomicAdd(&counts[i3], 1.0f);
  }
  #pragma unroll
  for (int off = 32; off; off >>= 1) l += __shfl_down(l, off);
  int lane = threadIdx.x & 63, w = threadIdx.x >> 6;
  if (lane == 0) sc[w] = l;
  __syncthreads();
  if (threadIdx.x == 0)
    atomicAdd(&ws[WS_LOSS], sc[0] + sc[1] + sc[2] + sc[3]);
}

// ---------- finalize scalars ----------
__global__ void finalize_k(const float* __restrict__ ws, float* __restrict__ out) {
  __shared__ float sc[8];
  int t = threadIdx.x;
  float ent = 0.f;
  #pragma unroll
  for (int k = t; k < K; k += 256) {
    float em = ws[WS_CNT + k] * (1.0f / NN);
    ent += em * logf(em + 1e-10f);
  }
  float zd = ws[WS_ZSUM + t] * ws[WS_ESUM + t];
  #pragma unroll
  for (int off = 32; off; off >>= 1) {
    ent += __shfl_down(ent, off);
    zd  += __shfl_down(zd, off);
  }
  int lane = t & 63, w = t >> 6;
  if (lane == 0) { sc[w] = ent; sc[4 + w] = zd; }
  __syncthreads();
  if (t == 0) {
    ent = sc[0] + sc[1] + sc[2] + sc[3];
    zd  = sc[4] + sc[5] + sc[6] + sc[7];
    out[OUT_LOSS] = 1.25f * ws[WS_LOSS] * (1.0f / ZQ_ELEMS);
    out[OUT_PERP] = expf(-ent);
    out[OUT_MD]   = ws[WS_SZ2] * (1.0f / NN) + ws[WS_SE2] * (1.0f / K)
                  - 2.0f * zd * (1.0f / ((float)NN * (float)K));
  }
}

extern "C" void kernel_launch(void* const* d_in, const int* in_sizes, int n_in,
                              void* d_out, int out_size, void* d_ws, size_t ws_size,
                              hipStream_t stream) {
  const float* z   = (const float*)d_in[0];
  const float* emb = (const float*)d_in[1];
  float* out = (float*)d_out;
  float* ws  = (float*)d_ws;
  int* flags = (int*)(ws + WS_FLG);
  u16* eh_g = (u16*)(ws + WS_EH);
  u16* el_g = (u16*)(ws + WS_EL);
  // zh/zl live in d_out's zq region; overwritten by gather_loss_k at the end.
  u16* zh_g = (u16*)d_out;
  u16* zl_g = zh_g + (size_t)ZQ_ELEMS;
  (void)in_sizes; (void)n_in; (void)out_size; (void)ws_size;

  hipMemsetAsync(d_ws, 0, WS_E2R * sizeof(float), stream);
  hipMemsetAsync(ws + WS_FLG, 0, sizeof(int), stream);
  emb_prep_k<<<64, 256, 0, stream>>>(emb, ws, eh_g, el_g);
  prep_z_k<<<NN / MROWS, 256, 0, stream>>>(z, ws, zh_g, zl_g);
  size_t lds = (size_t)(BM * 128 + BN * 128) * sizeof(u16) + 1024 * sizeof(float);
  vq_mfma_k<<<NN / BM, 256, lds, stream>>>(zh_g, zl_g, eh_g, el_g,
                                           ws + WS_E2R, out + OUT_IDX, flags);
  fixup_k<<<2048, 256, 0, stream>>>(z, emb, ws + WS_E2R, ws + WS_Z2N, flags, out + OUT_IDX);
  gather_loss_k<<<ZQ_ELEMS / 1024, 256, 0, stream>>>(z, emb, out, ws, ws + WS_CNT);
  finalize_k<<<1, 256, 0, stream>>>(ws, out);
}

// Round 7
// 332.077 us; speedup vs baseline: 1.4998x; 1.4998x over previous
//
#include <hip/hip_runtime.h>
#include <math.h>

// Problem constants
#define C 256
#define K 1024
#define SS 4096          // 16*16*16 spatial
#define NB 8             // batch
#define NN 32768         // NB*SS rows
#define ZQ_ELEMS 8388608 // NB*C*SS
#define OUT_LOSS 8388608
#define OUT_PERP 8388609
#define OUT_IDX  8388610
#define OUT_MD   8421378

// workspace float layout
#define WS_SZ2   0       // sum z^2 (scalar)
#define WS_SE2   1       // sum e^2 (scalar)
#define WS_LOSS  2       // sum (zq-z)^2 (scalar)
#define WS_ZSUM  8       // [256] column sums of zf
#define WS_ESUM  264     // [256] column sums of emb
#define WS_CNT   520     // [1024] histogram (float)
#define WS_E2R   1544    // [1024] ||e_k||^2, numpy-pairwise f32
#define WS_Z2N   2568    // [32768] ||z_n||^2, numpy-pairwise f32
#define WS_FLG   35336   // int region: [0]=count, [1..NN]=rows
#define WS_EH    68608   // [1024*256] u16 emb-hi
#define WS_EL    199680  // [1024*256] u16 emb-lo

#define T_FLAG 1.0e-4f

typedef __attribute__((ext_vector_type(8))) short short8;
typedef __attribute__((ext_vector_type(4))) float f32x4;
typedef unsigned short u16;

__device__ inline u16 f2bf(float x) {  // f32 -> bf16 RNE
  unsigned u = __float_as_uint(x);
  unsigned r = (u + 0x7fffu + ((u >> 16) & 1u)) >> 16;
  return (u16)r;
}
__device__ inline float bf2f(u16 h) { return __uint_as_float(((unsigned)h) << 16); }

// ---- numpy pairwise f32 sum of squares, 256 contiguous elements ----
__device__ inline float np_sumsq_256(const float* __restrict__ a) {
  float tot = 0.f;
  #pragma unroll
  for (int h = 0; h < 2; ++h) {
    const float* p = a + 128 * h;
    float r[8];
    #pragma unroll
    for (int j = 0; j < 8; ++j) r[j] = __fmul_rn(p[j], p[j]);
    for (int i = 8; i < 128; i += 8) {
      #pragma unroll
      for (int j = 0; j < 8; ++j) {
        float v = p[i + j];
        r[j] = __fadd_rn(r[j], __fmul_rn(v, v));
      }
    }
    float s01 = __fadd_rn(r[0], r[1]);
    float s23 = __fadd_rn(r[2], r[3]);
    float s45 = __fadd_rn(r[4], r[5]);
    float s67 = __fadd_rn(r[6], r[7]);
    float res = __fadd_rn(__fadd_rn(s01, s23), __fadd_rn(s45, s67));
    tot = (h == 0) ? res : __fadd_rn(tot, res);
  }
  return tot;
}

// ---------- emb prep: split to eh/el, e2[k], col sums, Se2 ----------
__global__ __launch_bounds__(256)
void emb_prep_k(const float* __restrict__ emb, float* __restrict__ ws,
                u16* __restrict__ eh, u16* __restrict__ el) {
  int r0 = blockIdx.x * 16;   // 64 blocks x 16 rows
  int t = threadIdx.x;
  float s = 0.f;
  #pragma unroll
  for (int i = 0; i < 16; ++i) {
    size_t idx = (size_t)(r0 + i) * C + t;
    float v = emb[idx];
    s += v;
    u16 h = f2bf(v);
    eh[idx] = h;
    el[idx] = f2bf(v - bf2f(h));
  }
  atomicAdd(&ws[WS_ESUM + t], s);
  if (t < 16) {
    float e2 = np_sumsq_256(emb + (size_t)(r0 + t) * C);
    ws[WS_E2R + r0 + t] = e2;
    atomicAdd(&ws[WS_SE2], e2);
  }
}

#define MROWS 64
#define ZS_STRIDE 260

// ---------- one pass over z: zsum[c], Sz2, z2np[n], bf16 split zh/zl ----------
__global__ __launch_bounds__(256)
void prep_z_k(const float* __restrict__ z, float* __restrict__ ws,
              u16* __restrict__ zh_g, u16* __restrict__ zl_g) {
  __shared__ float zs[MROWS * ZS_STRIDE];
  const int t = threadIdx.x;
  const int n0 = blockIdx.x * MROWS;
  const int b = n0 / SS;
  const int s0 = n0 % SS;
  {
    const int sl = t & 63, cg = t >> 6;
    const float* zb = z + (size_t)b * C * SS + s0 + sl;
    #pragma unroll
    for (int i = 0; i < 16; ++i) {
      int c = (cg * 16 + i) * 4;
      float4 v;
      v.x = zb[(size_t)(c + 0) * SS];
      v.y = zb[(size_t)(c + 1) * SS];
      v.z = zb[(size_t)(c + 2) * SS];
      v.w = zb[(size_t)(c + 3) * SS];
      *(float4*)&zs[sl * ZS_STRIDE + c] = v;
    }
  }
  __syncthreads();
  // column sums
  {
    float s = 0.f;
    #pragma unroll 8
    for (int r = 0; r < MROWS; ++r) s += zs[r * ZS_STRIDE + t];
    atomicAdd(&ws[WS_ZSUM + t], s);
  }
  // bf16 split, lane-linear coalesced short8 stores
  {
    #pragma unroll
    for (int i = 0; i < 8; ++i) {
      int q = i * 256 + t;          // short8 chunk 0..2047
      int row = q >> 5;             // 0..63
      int c0 = (q & 31) * 8;
      float4 va = *(const float4*)&zs[row * ZS_STRIDE + c0];
      float4 vb = *(const float4*)&zs[row * ZS_STRIDE + c0 + 4];
      float f[8] = {va.x, va.y, va.z, va.w, vb.x, vb.y, vb.z, vb.w};
      short8 hv, lv;
      #pragma unroll
      for (int j = 0; j < 8; ++j) {
        u16 h = f2bf(f[j]);
        hv[j] = (short)h;
        lv[j] = (short)f2bf(f[j] - bf2f(h));
      }
      size_t off = (size_t)(n0 + row) * C + c0;
      *(short8*)&zh_g[off] = hv;
      *(short8*)&zl_g[off] = lv;
    }
  }
  // z2 (numpy-pairwise) + Sz2
  if (t < MROWS) {
    float z2 = np_sumsq_256(&zs[t * ZS_STRIDE]);
    ws[WS_Z2N + n0 + t] = z2;
    #pragma unroll
    for (int off = 32; off; off >>= 1) z2 += __shfl_down(z2, off);
    if (t == 0) atomicAdd(&ws[WS_SZ2], z2);
  }
}

// ---------- main: split-bf16 MFMA distances + top-2 argmin + flags ----------
// R5-verified shape: grid 256 x 256, BM=128, BN=128, CH=64. Wave w owns rows
// w*32..+31 (mi 0..1) x ALL 128 cols (ni 0..7). 66 KB LDS -> 2 blocks/CU
// (the R6 regression showed 1 block/CU kills the implicit overlap).
#define BM 128
#define BN 128
#define CH 64

__global__ __launch_bounds__(256)
void vq_mfma_k(const u16* __restrict__ zh_g, const u16* __restrict__ zl_g,
               const u16* __restrict__ eh_g, const u16* __restrict__ el_g,
               const float* __restrict__ e2row, float* __restrict__ out_idx,
               int* __restrict__ flags) {
  extern __shared__ u16 smem_u16[];
  u16* Ah = smem_u16;            // [128 rows][64 c], swizzled
  u16* Al = Ah + BM * CH;
  u16* Bh = Al + BM * CH;
  u16* Bl = Bh + BN * CH;
  float* e2s = (float*)(Bl + BN * CH);  // [128]

  const int t = threadIdx.x;
  const int lane = t & 63;
  const int wid = t >> 6;        // wave owns rows wid*32..wid*32+31
  const int row0 = blockIdx.x * BM;

  float v1[8], v2[8], i1f[8];
  #pragma unroll
  for (int s = 0; s < 8; ++s) { v1[s] = 3.4e38f; v2[s] = 3.4e38f; i1f[s] = 0.f; }

  for (int nt = 0; nt < K / BN; ++nt) {
    const int kc0 = nt * BN;
    __syncthreads();                 // prior n-tile's e2s readers done
    if (t < BN) e2s[t] = e2row[kc0 + t];

    f32x4 acc[2][8];
    #pragma unroll
    for (int mi = 0; mi < 2; ++mi)
      #pragma unroll
      for (int ni = 0; ni < 8; ++ni) acc[mi][ni] = (f32x4){0.f, 0.f, 0.f, 0.f};

    for (int ch = 0; ch < C / CH; ++ch) {
      const int c0 = ch * CH;
      __syncthreads();               // prior chunk's frag readers done
      // ---- stage A and B: pure short8 copies of pre-split data ----
      {
        const int g = t & 7;
        #pragma unroll
        for (int r = 0; r < 4; ++r) {
          int row = (t >> 3) + 32 * r;            // 0..127
          int jpos = g ^ (row & 7);               // swizzle
          size_t srcA = (size_t)(row0 + row) * C + c0 + g * 8;
          *(short8*)&Ah[row * CH + jpos * 8] = *(const short8*)&zh_g[srcA];
          *(short8*)&Al[row * CH + jpos * 8] = *(const short8*)&zl_g[srcA];
          size_t srcB = (size_t)(kc0 + row) * C + c0 + g * 8;
          *(short8*)&Bh[row * CH + jpos * 8] = *(const short8*)&eh_g[srcB];
          *(short8*)&Bl[row * CH + jpos * 8] = *(const short8*)&el_g[srcB];
        }
      }
      __syncthreads();
      // ---- compute: 2 k-steps of 32 ----
      #pragma unroll
      for (int s = 0; s < 2; ++s) {
        const int q = s * 4 + (lane >> 4);
        short8 afh[2], afl[2];
        #pragma unroll
        for (int mi = 0; mi < 2; ++mi) {
          int rowl = wid * 32 + mi * 16 + (lane & 15);
          int jp = q ^ (rowl & 7);
          afh[mi] = *(short8*)&Ah[rowl * CH + jp * 8];
          afl[mi] = *(short8*)&Al[rowl * CH + jp * 8];
        }
        #pragma unroll
        for (int ni = 0; ni < 8; ++ni) {
          int rowb = ni * 16 + (lane & 15);
          int jp = q ^ (rowb & 7);
          short8 bh = *(short8*)&Bh[rowb * CH + jp * 8];
          short8 bl = *(short8*)&Bl[rowb * CH + jp * 8];
          #pragma unroll
          for (int mi = 0; mi < 2; ++mi) {
            acc[mi][ni] = __builtin_amdgcn_mfma_f32_16x16x32_bf16(afh[mi], bh, acc[mi][ni], 0, 0, 0);
            acc[mi][ni] = __builtin_amdgcn_mfma_f32_16x16x32_bf16(afh[mi], bl, acc[mi][ni], 0, 0, 0);
            acc[mi][ni] = __builtin_amdgcn_mfma_f32_16x16x32_bf16(afl[mi], bh, acc[mi][ni], 0, 0, 0);
          }
        }
      }
    }
    // ---- scoring: u = e2 - 2*g ; running top-2 per row-slot ----
    #pragma unroll
    for (int ni = 0; ni < 8; ++ni) {
      int col = ni * 16 + (lane & 15);
      float e2c = e2s[col];
      float kidx = (float)(kc0 + col);
      #pragma unroll
      for (int mi = 0; mi < 2; ++mi)
        #pragma unroll
        for (int r = 0; r < 4; ++r) {
          float sv = fmaf(-2.f, acc[mi][ni][r], e2c);
          int slot = mi * 4 + r;
          if (sv < v1[slot]) { v2[slot] = v1[slot]; v1[slot] = sv; i1f[slot] = kidx; }
          else if (sv < v2[slot]) v2[slot] = sv;
        }
    }
  }
  // ---- butterfly top-2 merge over the 16 lanes sharing (lane>>4) ----
  #pragma unroll
  for (int off = 1; off < 16; off <<= 1) {
    #pragma unroll
    for (int s = 0; s < 8; ++s) {
      float ov1 = __shfl_xor(v1[s], off);
      float oi1 = __shfl_xor(i1f[s], off);
      float ov2 = __shfl_xor(v2[s], off);
      bool take = (ov1 < v1[s]) || (ov1 == v1[s] && oi1 < i1f[s]);
      float nv2 = fminf(take ? v1[s] : v2[s], take ? ov2 : ov1);
      if (take) { v1[s] = ov1; i1f[s] = oi1; }
      v2[s] = nv2;
    }
  }
  if ((lane & 15) == 0) {
    int q = lane >> 4;
    #pragma unroll
    for (int mi = 0; mi < 2; ++mi)
      #pragma unroll
      for (int r = 0; r < 4; ++r) {
        int slot = mi * 4 + r;
        int row = row0 + wid * 32 + mi * 16 + q * 4 + r;
        out_idx[row] = i1f[slot];
        if (v2[slot] - v1[slot] < T_FLAG) {
          int p = atomicAdd(&flags[0], 1);
          if (p < NN) flags[1 + p] = row;
        }
      }
  }
}

// ---------- fixup: exactly-rounded f32 dot (via f64) + quantized formula ----------
__global__ __launch_bounds__(256)
void fixup_k(const float* __restrict__ z, const float* __restrict__ emb,
             const float* __restrict__ e2np, const float* __restrict__ z2np,
             const int* __restrict__ flags, float* __restrict__ out_idx) {
  __shared__ float zrow[C];
  __shared__ float bval[4];
  __shared__ int   bidx[4];
  int cnt = flags[0];
  if (cnt > NN) cnt = NN;
  for (int f = blockIdx.x; f < cnt; f += gridDim.x) {
    int n = flags[1 + f];
    int b = n >> 12, s = n & (SS - 1);
    int t = threadIdx.x;
    zrow[t] = z[((size_t)(b * C + t) << 12) + s];
    __syncthreads();
    float z2 = z2np[n];
    float best = 3.4e38f; int besti = 0x7fffffff;
    for (int kk = t; kk < K; kk += 256) {
      const float* er = emb + (size_t)kk * C;
      double acc = 0.0;
      #pragma unroll 4
      for (int c = 0; c < C; ++c)
        acc = fma((double)zrow[c], (double)er[c], acc);
      float g  = (float)acc;
      float t1 = __fadd_rn(z2, e2np[kk]);
      float d  = __fsub_rn(t1, __fmul_rn(2.f, g));
      if (d < best) { best = d; besti = kk; }
    }
    #pragma unroll
    for (int off = 32; off; off >>= 1) {
      float ov = __shfl_down(best, off);
      int   oi = __shfl_down(besti, off);
      if (ov < best || (ov == best && oi < besti)) { best = ov; besti = oi; }
    }
    int lane = t & 63, w = t >> 6;
    if (lane == 0) { bval[w] = best; bidx[w] = besti; }
    __syncthreads();
    if (t == 0) {
      #pragma unroll
      for (int w2 = 1; w2 < 4; ++w2) {
        if (bval[w2] < best || (bval[w2] == best && bidx[w2] < besti)) {
          best = bval[w2]; besti = bidx[w2];
        }
      }
      out_idx[n] = (float)besti;
    }
    __syncthreads();
  }
}

// ---------- gather via LDS-staged emb rows + loss + histogram ----------
// block = 64 rows (one b, s0..s0+63). Stage the 64 selected emb rows into
// LDS (stride 257 -> conflict-free column reads), then write zq coalesced
// (256B per c along s). Kills the 33M random dword gathers of the old kernel.
#define GROWS 64
__global__ __launch_bounds__(256)
void gather2_k(const float* __restrict__ z, const float* __restrict__ emb,
               float* __restrict__ out, float* __restrict__ ws,
               float* __restrict__ counts) {
  __shared__ float eb[GROWS * 257];
  __shared__ int idxs[GROWS];
  __shared__ float sc[4];
  const int t = threadIdx.x;
  const int n0 = blockIdx.x * GROWS;
  const int b = n0 >> 12;
  const int s0 = n0 & (SS - 1);
  if (t < GROWS) {
    int id = (int)out[OUT_IDX + n0 + t];
    idxs[t] = id;
    atomicAdd(&counts[id], 1.0f);
  }
  __syncthreads();
  // stage emb rows: 4096 float4 chunks, coalesced (16 lanes x 16B per row seg)
  #pragma unroll
  for (int i = 0; i < 16; ++i) {
    int q = i * 256 + t;
    int row = q >> 6, c4 = q & 63;
    float4 v = *(const float4*)&emb[(size_t)idxs[row] * C + c4 * 4];
    int base = row * 257 + c4 * 4;
    eb[base + 0] = v.x; eb[base + 1] = v.y;
    eb[base + 2] = v.z; eb[base + 3] = v.w;
  }
  __syncthreads();
  const int sl = t & 63, cg = t >> 6;
  const float* zb = z + (size_t)b * C * SS + s0 + sl;
  float* ob = out + (size_t)b * C * SS + s0 + sl;
  float l = 0.f;
  #pragma unroll 4
  for (int i = 0; i < 64; ++i) {
    int c = cg * 64 + i;
    float q = eb[sl * 257 + c];
    float zv = zb[(size_t)c * SS];
    float d = q - zv;
    l += d * d;
    ob[(size_t)c * SS] = q;
  }
  #pragma unroll
  for (int off = 32; off; off >>= 1) l += __shfl_down(l, off);
  int lane = t & 63, w = t >> 6;
  if (lane == 0) sc[w] = l;
  __syncthreads();
  if (t == 0)
    atomicAdd(&ws[WS_LOSS], sc[0] + sc[1] + sc[2] + sc[3]);
}

// ---------- finalize scalars ----------
__global__ void finalize_k(const float* __restrict__ ws, float* __restrict__ out) {
  __shared__ float sc[8];
  int t = threadIdx.x;
  float ent = 0.f;
  #pragma unroll
  for (int k = t; k < K; k += 256) {
    float em = ws[WS_CNT + k] * (1.0f / NN);
    ent += em * logf(em + 1e-10f);
  }
  float zd = ws[WS_ZSUM + t] * ws[WS_ESUM + t];
  #pragma unroll
  for (int off = 32; off; off >>= 1) {
    ent += __shfl_down(ent, off);
    zd  += __shfl_down(zd, off);
  }
  int lane = t & 63, w = t >> 6;
  if (lane == 0) { sc[w] = ent; sc[4 + w] = zd; }
  __syncthreads();
  if (t == 0) {
    ent = sc[0] + sc[1] + sc[2] + sc[3];
    zd  = sc[4] + sc[5] + sc[6] + sc[7];
    out[OUT_LOSS] = 1.25f * ws[WS_LOSS] * (1.0f / ZQ_ELEMS);
    out[OUT_PERP] = expf(-ent);
    out[OUT_MD]   = ws[WS_SZ2] * (1.0f / NN) + ws[WS_SE2] * (1.0f / K)
                  - 2.0f * zd * (1.0f / ((float)NN * (float)K));
  }
}

extern "C" void kernel_launch(void* const* d_in, const int* in_sizes, int n_in,
                              void* d_out, int out_size, void* d_ws, size_t ws_size,
                              hipStream_t stream) {
  const float* z   = (const float*)d_in[0];
  const float* emb = (const float*)d_in[1];
  float* out = (float*)d_out;
  float* ws  = (float*)d_ws;
  int* flags = (int*)(ws + WS_FLG);
  u16* eh_g = (u16*)(ws + WS_EH);
  u16* el_g = (u16*)(ws + WS_EL);
  // zh/zl live in d_out's zq region; overwritten by gather2_k at the end.
  u16* zh_g = (u16*)d_out;
  u16* zl_g = zh_g + (size_t)ZQ_ELEMS;
  (void)in_sizes; (void)n_in; (void)out_size; (void)ws_size;

  hipMemsetAsync(d_ws, 0, WS_E2R * sizeof(float), stream);
  hipMemsetAsync(ws + WS_FLG, 0, sizeof(int), stream);
  emb_prep_k<<<64, 256, 0, stream>>>(emb, ws, eh_g, el_g);
  prep_z_k<<<NN / MROWS, 256, 0, stream>>>(z, ws, zh_g, zl_g);
  size_t lds = (size_t)(4 * BM * CH) * sizeof(u16) + BN * sizeof(float);
  vq_mfma_k<<<NN / BM, 256, lds, stream>>>(zh_g, zl_g, eh_g, el_g,
                                           ws + WS_E2R, out + OUT_IDX, flags);
  fixup_k<<<2048, 256, 0, stream>>>(z, emb, ws + WS_E2R, ws + WS_Z2N, flags, out + OUT_IDX);
  gather2_k<<<NN / GROWS, 256, 0, stream>>>(z, emb, out, ws, ws + WS_CNT);
  finalize_k<<<1, 256, 0, stream>>>(ws, out);
}

// Round 8
// 298.320 us; speedup vs baseline: 1.6695x; 1.1132x over previous
//
#include <hip/hip_runtime.h>
#include <math.h>

// Problem constants
#define C 256
#define K 1024
#define SS 4096          // 16*16*16 spatial
#define NB 8             // batch
#define NN 32768         // NB*SS rows
#define ZQ_ELEMS 8388608 // NB*C*SS
#define OUT_LOSS 8388608
#define OUT_PERP 8388609
#define OUT_IDX  8388610
#define OUT_MD   8421378

// workspace float layout
#define WS_SZ2   0       // sum z^2 (scalar)
#define WS_SE2   1       // sum e^2 (scalar)
#define WS_LOSS  2       // sum (zq-z)^2 (scalar)
#define WS_ZSUM  8       // [256] column sums of zf
#define WS_ESUM  264     // [256] column sums of emb
#define WS_CNT   520     // [1024] histogram (float)
#define WS_E2R   1544    // [1024] ||e_k||^2, numpy-pairwise f32
#define WS_Z2N   2568    // [32768] ||z_n||^2, numpy-pairwise f32
#define WS_FLG   35336   // int region: [0]=count, [1..NN]=rows
#define WS_EH    68608   // [1024*256] u16 emb-hi
#define WS_EL    199680  // [1024*256] u16 emb-lo

#define T_FLAG 1.0e-4f

typedef __attribute__((ext_vector_type(8))) short short8;
typedef __attribute__((ext_vector_type(4))) float f32x4;
typedef unsigned short u16;

__device__ inline u16 f2bf(float x) {  // f32 -> bf16 RNE
  unsigned u = __float_as_uint(x);
  unsigned r = (u + 0x7fffu + ((u >> 16) & 1u)) >> 16;
  return (u16)r;
}
__device__ inline float bf2f(u16 h) { return __uint_as_float(((unsigned)h) << 16); }

// ---- numpy pairwise f32 sum of squares, 256 contiguous elements ----
__device__ inline float np_sumsq_256(const float* __restrict__ a) {
  float tot = 0.f;
  #pragma unroll
  for (int h = 0; h < 2; ++h) {
    const float* p = a + 128 * h;
    float r[8];
    #pragma unroll
    for (int j = 0; j < 8; ++j) r[j] = __fmul_rn(p[j], p[j]);
    for (int i = 8; i < 128; i += 8) {
      #pragma unroll
      for (int j = 0; j < 8; ++j) {
        float v = p[i + j];
        r[j] = __fadd_rn(r[j], __fmul_rn(v, v));
      }
    }
    float s01 = __fadd_rn(r[0], r[1]);
    float s23 = __fadd_rn(r[2], r[3]);
    float s45 = __fadd_rn(r[4], r[5]);
    float s67 = __fadd_rn(r[6], r[7]);
    float res = __fadd_rn(__fadd_rn(s01, s23), __fadd_rn(s45, s67));
    tot = (h == 0) ? res : __fadd_rn(tot, res);
  }
  return tot;
}

// ---------- emb prep: split to eh/el, e2[k], col sums, Se2 ----------
__global__ __launch_bounds__(256)
void emb_prep_k(const float* __restrict__ emb, float* __restrict__ ws,
                u16* __restrict__ eh, u16* __restrict__ el) {
  int r0 = blockIdx.x * 16;   // 64 blocks x 16 rows
  int t = threadIdx.x;
  float s = 0.f;
  #pragma unroll
  for (int i = 0; i < 16; ++i) {
    size_t idx = (size_t)(r0 + i) * C + t;
    float v = emb[idx];
    s += v;
    u16 h = f2bf(v);
    eh[idx] = h;
    el[idx] = f2bf(v - bf2f(h));
  }
  atomicAdd(&ws[WS_ESUM + t], s);
  if (t < 16) {
    float e2 = np_sumsq_256(emb + (size_t)(r0 + t) * C);
    ws[WS_E2R + r0 + t] = e2;
    atomicAdd(&ws[WS_SE2], e2);
  }
}

#define MROWS 64
#define ZS_STRIDE 260

// ---------- one pass over z: zsum[c], Sz2, z2np[n], bf16 split zh/zl ----------
__global__ __launch_bounds__(256)
void prep_z_k(const float* __restrict__ z, float* __restrict__ ws,
              u16* __restrict__ zh_g, u16* __restrict__ zl_g) {
  __shared__ float zs[MROWS * ZS_STRIDE];
  const int t = threadIdx.x;
  const int n0 = blockIdx.x * MROWS;
  const int b = n0 / SS;
  const int s0 = n0 % SS;
  {
    const int sl = t & 63, cg = t >> 6;
    const float* zb = z + (size_t)b * C * SS + s0 + sl;
    #pragma unroll
    for (int i = 0; i < 16; ++i) {
      int c = (cg * 16 + i) * 4;
      float4 v;
      v.x = zb[(size_t)(c + 0) * SS];
      v.y = zb[(size_t)(c + 1) * SS];
      v.z = zb[(size_t)(c + 2) * SS];
      v.w = zb[(size_t)(c + 3) * SS];
      *(float4*)&zs[sl * ZS_STRIDE + c] = v;
    }
  }
  __syncthreads();
  // column sums
  {
    float s = 0.f;
    #pragma unroll 8
    for (int r = 0; r < MROWS; ++r) s += zs[r * ZS_STRIDE + t];
    atomicAdd(&ws[WS_ZSUM + t], s);
  }
  // bf16 split, lane-linear coalesced short8 stores
  {
    #pragma unroll
    for (int i = 0; i < 8; ++i) {
      int q = i * 256 + t;          // short8 chunk 0..2047
      int row = q >> 5;             // 0..63
      int c0 = (q & 31) * 8;
      float4 va = *(const float4*)&zs[row * ZS_STRIDE + c0];
      float4 vb = *(const float4*)&zs[row * ZS_STRIDE + c0 + 4];
      float f[8] = {va.x, va.y, va.z, va.w, vb.x, vb.y, vb.z, vb.w};
      short8 hv, lv;
      #pragma unroll
      for (int j = 0; j < 8; ++j) {
        u16 h = f2bf(f[j]);
        hv[j] = (short)h;
        lv[j] = (short)f2bf(f[j] - bf2f(h));
      }
      size_t off = (size_t)(n0 + row) * C + c0;
      *(short8*)&zh_g[off] = hv;
      *(short8*)&zl_g[off] = lv;
    }
  }
  // z2 (numpy-pairwise) + Sz2
  if (t < MROWS) {
    float z2 = np_sumsq_256(&zs[t * ZS_STRIDE]);
    ws[WS_Z2N + n0 + t] = z2;
    #pragma unroll
    for (int off = 32; off; off >>= 1) z2 += __shfl_down(z2, off);
    if (t == 0) atomicAdd(&ws[WS_SZ2], z2);
  }
}

// ---------- main: split-bf16 MFMA distances + top-2 argmin + flags ----------
// BM=64 -> grid 512 -> 2 blocks/CU co-resident (the R7 grid of 256 pinned
// occupancy at 1 block/CU and left every staging barrier latency-exposed).
// Waves 2x2: wave(wm,wn) = rows wm*32..+31 (mi 0..1) x cols wn*64..+63
// (ni 0..3). Col halves merged at the end via LDS. ~50 KB LDS.
#define BM 64
#define BN 128
#define CH 64

__global__ __launch_bounds__(256, 2)
void vq_mfma_k(const u16* __restrict__ zh_g, const u16* __restrict__ zl_g,
               const u16* __restrict__ eh_g, const u16* __restrict__ el_g,
               const float* __restrict__ e2row, float* __restrict__ out_idx,
               int* __restrict__ flags) {
  extern __shared__ u16 smem_u16[];
  u16* Ah = smem_u16;                 // [64][64] u16, swizzled
  u16* Al = Ah + BM * CH;
  u16* Bh = Al + BM * CH;             // [128][64]
  u16* Bl = Bh + BN * CH;
  float* e2s = (float*)(Bl + BN * CH);   // [128]
  float* mv1 = e2s + BN;              // [2][64] col-half merge
  float* mv2 = mv1 + 2 * BM;
  float* mi1 = mv2 + 2 * BM;

  const int t = threadIdx.x;
  const int lane = t & 63;
  const int wid = t >> 6;
  const int wm = wid >> 1, wn = wid & 1;
  const int quad = lane >> 4, lr = lane & 15;
  const int row0 = blockIdx.x * BM;

  // running top-2 per slot (mi*4 + r), cols restricted to this wave's half
  float v1[8], v2[8], i1f[8];
  #pragma unroll
  for (int s = 0; s < 8; ++s) { v1[s] = 3.4e38f; v2[s] = 3.4e38f; i1f[s] = 0.f; }

  for (int nt = 0; nt < K / BN; ++nt) {
    const int kc0 = nt * BN;
    __syncthreads();                 // prior n-tile's e2s readers done
    if (t < BN) e2s[t] = e2row[kc0 + t];

    f32x4 acc[2][4];
    #pragma unroll
    for (int mi = 0; mi < 2; ++mi)
      #pragma unroll
      for (int ni = 0; ni < 4; ++ni) acc[mi][ni] = (f32x4){0.f, 0.f, 0.f, 0.f};

    for (int ch = 0; ch < C / CH; ++ch) {
      const int c0 = ch * CH;
      __syncthreads();               // prior chunk's frag readers done
      // ---- stage A: 512 granules x2 (h,l) ----
      #pragma unroll
      for (int i = 0; i < 2; ++i) {
        int G = i * 256 + t;
        int row = G >> 3, g = G & 7;
        int jpos = g ^ (row & 7);
        size_t src = (size_t)(row0 + row) * C + c0 + g * 8;
        *(short8*)&Ah[row * CH + jpos * 8] = *(const short8*)&zh_g[src];
        *(short8*)&Al[row * CH + jpos * 8] = *(const short8*)&zl_g[src];
      }
      // ---- stage B: 1024 granules x2 (h,l) ----
      #pragma unroll
      for (int i = 0; i < 4; ++i) {
        int G = i * 256 + t;
        int row = G >> 3, g = G & 7;
        int jpos = g ^ (row & 7);
        size_t src = (size_t)(kc0 + row) * C + c0 + g * 8;
        *(short8*)&Bh[row * CH + jpos * 8] = *(const short8*)&eh_g[src];
        *(short8*)&Bl[row * CH + jpos * 8] = *(const short8*)&el_g[src];
      }
      __syncthreads();
      // ---- compute: 2 k-steps of 32 ----
      #pragma unroll
      for (int s = 0; s < 2; ++s) {
        const int q = s * 4 + quad;
        short8 afh[2], afl[2];
        #pragma unroll
        for (int mi = 0; mi < 2; ++mi) {
          int rowl = wm * 32 + mi * 16 + lr;
          int jp = q ^ (rowl & 7);
          afh[mi] = *(short8*)&Ah[rowl * CH + jp * 8];
          afl[mi] = *(short8*)&Al[rowl * CH + jp * 8];
        }
        #pragma unroll
        for (int ni = 0; ni < 4; ++ni) {
          int rowb = wn * 64 + ni * 16 + lr;
          int jp = q ^ (rowb & 7);
          short8 bh = *(short8*)&Bh[rowb * CH + jp * 8];
          short8 bl = *(short8*)&Bl[rowb * CH + jp * 8];
          #pragma unroll
          for (int mi = 0; mi < 2; ++mi) {
            acc[mi][ni] = __builtin_amdgcn_mfma_f32_16x16x32_bf16(afh[mi], bh, acc[mi][ni], 0, 0, 0);
            acc[mi][ni] = __builtin_amdgcn_mfma_f32_16x16x32_bf16(afh[mi], bl, acc[mi][ni], 0, 0, 0);
            acc[mi][ni] = __builtin_amdgcn_mfma_f32_16x16x32_bf16(afl[mi], bh, acc[mi][ni], 0, 0, 0);
          }
        }
      }
    }
    // ---- scoring: u = e2 - 2*g ; running top-2 per row-slot ----
    #pragma unroll
    for (int ni = 0; ni < 4; ++ni) {
      int col = wn * 64 + ni * 16 + lr;
      float e2c = e2s[col];
      float kidx = (float)(kc0 + col);
      #pragma unroll
      for (int mi = 0; mi < 2; ++mi)
        #pragma unroll
        for (int r = 0; r < 4; ++r) {
          float sv = fmaf(-2.f, acc[mi][ni][r], e2c);
          int slot = mi * 4 + r;
          if (sv < v1[slot]) { v2[slot] = v1[slot]; v1[slot] = sv; i1f[slot] = kidx; }
          else if (sv < v2[slot]) v2[slot] = sv;
        }
    }
  }
  // ---- butterfly top-2 merge over the 16 col lanes (lr) ----
  #pragma unroll
  for (int off = 1; off < 16; off <<= 1) {
    #pragma unroll
    for (int s = 0; s < 8; ++s) {
      float ov1 = __shfl_xor(v1[s], off);
      float oi1 = __shfl_xor(i1f[s], off);
      float ov2 = __shfl_xor(v2[s], off);
      bool take = (ov1 < v1[s]) || (ov1 == v1[s] && oi1 < i1f[s]);
      float nv2 = fminf(take ? v1[s] : v2[s], take ? ov2 : ov1);
      if (take) { v1[s] = ov1; i1f[s] = oi1; }
      v2[s] = nv2;
    }
  }
  // ---- write per-wave (col-half) results to LDS, then merge halves ----
  __syncthreads();   // all waves done with staging buffers / compute
  if (lr == 0) {
    #pragma unroll
    for (int mi = 0; mi < 2; ++mi)
      #pragma unroll
      for (int r = 0; r < 4; ++r) {
        int slot = mi * 4 + r;
        int row = wm * 32 + mi * 16 + quad * 4 + r;   // 0..63
        mv1[wn * BM + row] = v1[slot];
        mv2[wn * BM + row] = v2[slot];
        mi1[wn * BM + row] = i1f[slot];
      }
  }
  __syncthreads();
  if (t < BM) {
    float a1 = mv1[t], ai = mi1[t], a2 = mv2[t];
    float c1 = mv1[BM + t], ci = mi1[BM + t], c2 = mv2[BM + t];
    bool take = (c1 < a1) || (c1 == a1 && ci < ai);
    float b1 = take ? c1 : a1;
    float bi = take ? ci : ai;
    float b2 = fminf(fminf(a2, c2), take ? a1 : c1);
    out_idx[row0 + t] = bi;
    if (b2 - b1 < T_FLAG) {
      int p = atomicAdd(&flags[0], 1);
      if (p < NN) flags[1 + p] = row0 + t;
    }
  }
}

// ---------- fixup: exactly-rounded f32 dot (via f64) + quantized formula ----------
__global__ __launch_bounds__(256)
void fixup_k(const float* __restrict__ z, const float* __restrict__ emb,
             const float* __restrict__ e2np, const float* __restrict__ z2np,
             const int* __restrict__ flags, float* __restrict__ out_idx) {
  __shared__ float zrow[C];
  __shared__ float bval[4];
  __shared__ int   bidx[4];
  int cnt = flags[0];
  if (cnt > NN) cnt = NN;
  for (int f = blockIdx.x; f < cnt; f += gridDim.x) {
    int n = flags[1 + f];
    int b = n >> 12, s = n & (SS - 1);
    int t = threadIdx.x;
    zrow[t] = z[((size_t)(b * C + t) << 12) + s];
    __syncthreads();
    float z2 = z2np[n];
    float best = 3.4e38f; int besti = 0x7fffffff;
    for (int kk = t; kk < K; kk += 256) {
      const float* er = emb + (size_t)kk * C;
      double acc = 0.0;
      #pragma unroll 4
      for (int c = 0; c < C; ++c)
        acc = fma((double)zrow[c], (double)er[c], acc);
      float g  = (float)acc;
      float t1 = __fadd_rn(z2, e2np[kk]);
      float d  = __fsub_rn(t1, __fmul_rn(2.f, g));
      if (d < best) { best = d; besti = kk; }
    }
    #pragma unroll
    for (int off = 32; off; off >>= 1) {
      float ov = __shfl_down(best, off);
      int   oi = __shfl_down(besti, off);
      if (ov < best || (ov == best && oi < besti)) { best = ov; besti = oi; }
    }
    int lane = t & 63, w = t >> 6;
    if (lane == 0) { bval[w] = best; bidx[w] = besti; }
    __syncthreads();
    if (t == 0) {
      #pragma unroll
      for (int w2 = 1; w2 < 4; ++w2) {
        if (bval[w2] < best || (bval[w2] == best && bidx[w2] < besti)) {
          best = bval[w2]; besti = bidx[w2];
        }
      }
      out_idx[n] = (float)besti;
    }
    __syncthreads();
  }
}

// ---------- gather via LDS-staged emb rows + loss + histogram ----------
#define GROWS 64
__global__ __launch_bounds__(256)
void gather2_k(const float* __restrict__ z, const float* __restrict__ emb,
               float* __restrict__ out, float* __restrict__ ws,
               float* __restrict__ counts) {
  __shared__ float eb[GROWS * 257];
  __shared__ int idxs[GROWS];
  __shared__ float sc[4];
  const int t = threadIdx.x;
  const int n0 = blockIdx.x * GROWS;
  const int b = n0 >> 12;
  const int s0 = n0 & (SS - 1);
  if (t < GROWS) {
    int id = (int)out[OUT_IDX + n0 + t];
    idxs[t] = id;
    atomicAdd(&counts[id], 1.0f);
  }
  __syncthreads();
  #pragma unroll
  for (int i = 0; i < 16; ++i) {
    int q = i * 256 + t;
    int row = q >> 6, c4 = q & 63;
    float4 v = *(const float4*)&emb[(size_t)idxs[row] * C + c4 * 4];
    int base = row * 257 + c4 * 4;
    eb[base + 0] = v.x; eb[base + 1] = v.y;
    eb[base + 2] = v.z; eb[base + 3] = v.w;
  }
  __syncthreads();
  const int sl = t & 63, cg = t >> 6;
  const float* zb = z + (size_t)b * C * SS + s0 + sl;
  float* ob = out + (size_t)b * C * SS + s0 + sl;
  float l = 0.f;
  #pragma unroll 4
  for (int i = 0; i < 64; ++i) {
    int c = cg * 64 + i;
    float q = eb[sl * 257 + c];
    float zv = zb[(size_t)c * SS];
    float d = q - zv;
    l += d * d;
    ob[(size_t)c * SS] = q;
  }
  #pragma unroll
  for (int off = 32; off; off >>= 1) l += __shfl_down(l, off);
  int lane = t & 63, w = t >> 6;
  if (lane == 0) sc[w] = l;
  __syncthreads();
  if (t == 0)
    atomicAdd(&ws[WS_LOSS], sc[0] + sc[1] + sc[2] + sc[3]);
}

// ---------- finalize scalars ----------
__global__ void finalize_k(const float* __restrict__ ws, float* __restrict__ out) {
  __shared__ float sc[8];
  int t = threadIdx.x;
  float ent = 0.f;
  #pragma unroll
  for (int k = t; k < K; k += 256) {
    float em = ws[WS_CNT + k] * (1.0f / NN);
    ent += em * logf(em + 1e-10f);
  }
  float zd = ws[WS_ZSUM + t] * ws[WS_ESUM + t];
  #pragma unroll
  for (int off = 32; off; off >>= 1) {
    ent += __shfl_down(ent, off);
    zd  += __shfl_down(zd, off);
  }
  int lane = t & 63, w = t >> 6;
  if (lane == 0) { sc[w] = ent; sc[4 + w] = zd; }
  __syncthreads();
  if (t == 0) {
    ent = sc[0] + sc[1] + sc[2] + sc[3];
    zd  = sc[4] + sc[5] + sc[6] + sc[7];
    out[OUT_LOSS] = 1.25f * ws[WS_LOSS] * (1.0f / ZQ_ELEMS);
    out[OUT_PERP] = expf(-ent);
    out[OUT_MD]   = ws[WS_SZ2] * (1.0f / NN) + ws[WS_SE2] * (1.0f / K)
                  - 2.0f * zd * (1.0f / ((float)NN * (float)K));
  }
}

extern "C" void kernel_launch(void* const* d_in, const int* in_sizes, int n_in,
                              void* d_out, int out_size, void* d_ws, size_t ws_size,
                              hipStream_t stream) {
  const float* z   = (const float*)d_in[0];
  const float* emb = (const float*)d_in[1];
  float* out = (float*)d_out;
  float* ws  = (float*)d_ws;
  int* flags = (int*)(ws + WS_FLG);
  u16* eh_g = (u16*)(ws + WS_EH);
  u16* el_g = (u16*)(ws + WS_EL);
  // zh/zl live in d_out's zq region; overwritten by gather2_k at the end.
  u16* zh_g = (u16*)d_out;
  u16* zl_g = zh_g + (size_t)ZQ_ELEMS;
  (void)in_sizes; (void)n_in; (void)out_size; (void)ws_size;

  hipMemsetAsync(d_ws, 0, WS_E2R * sizeof(float), stream);
  hipMemsetAsync(ws + WS_FLG, 0, sizeof(int), stream);
  emb_prep_k<<<64, 256, 0, stream>>>(emb, ws, eh_g, el_g);
  prep_z_k<<<NN / MROWS, 256, 0, stream>>>(z, ws, zh_g, zl_g);
  size_t lds = (size_t)(2 * BM * CH + 2 * BN * CH) * sizeof(u16)
             + (BN + 6 * BM) * sizeof(float);
  vq_mfma_k<<<NN / BM, 256, lds, stream>>>(zh_g, zl_g, eh_g, el_g,
                                           ws + WS_E2R, out + OUT_IDX, flags);
  fixup_k<<<2048, 256, 0, stream>>>(z, emb, ws + WS_E2R, ws + WS_Z2N, flags, out + OUT_IDX);
  gather2_k<<<NN / GROWS, 256, 0, stream>>>(z, emb, out, ws, ws + WS_CNT);
  finalize_k<<<1, 256, 0, stream>>>(ws, out);
}